// Round 14
// baseline (67.294 us; speedup 1.0000x reference)
//
#include <hip/hip_runtime.h>
#include <stdint.h>

#define N_ANCH 65648
#define NCHUNK 65          // k_bins chunks of 1024 anchors
#define CHUNK  1024
#define NQ16   4103        // 65648/16 exactly
#define NSLICE 8           // slices per batch in k_mid (9 chunks each, last=2)
#define SEGCAP 1024        // per-(batch,slice) segment capacity
#define CAP    1024        // candidates gathered in k_nms
#define KBASE  0xBE800000u // sortable key of 0.25; fg scores >= 1/3 -> bins in [42,255]
#define NBATCH 32
#define TOPK   100

struct Ptrs { const float* cls[8]; const float* reg[8]; };

__constant__ int   c_off[9] = {0,25281,50562,56803,63044,64565,64926,65287,65648};
__constant__ int   c_sz[8]  = {159,159,79,79,39,19,19,19};
__constant__ float c_st[8]  = {4.f,4.f,8.f,8.f,16.f,32.f,32.f,32.f};
__constant__ float c_rf[8]  = {27.5f,35.5f,55.5f,71.5f,111.5f,191.5f,255.5f,319.5f};

// sortable key for the masked score of anchor n in batch b; 0 if background.
// EXACT same fp sequence as all passing rounds.
__device__ inline uint32_t anchor_key(const Ptrs& p, int b, int n) {
  int k = 0;
#pragma unroll
  for (int q = 1; q < 8; ++q) if (n >= c_off[q]) k = q;
  int local = n - c_off[k];
  int hw = c_sz[k] * c_sz[k];
  const float* c = p.cls[k] + (size_t)(b * 3) * hw + local;
  float l0 = c[0], l1 = c[(size_t)hw], l2 = c[(size_t)2 * hw];
  float m = l0; int cl = 0;
  if (l1 > m) { m = l1; cl = 1; }
  if (l2 > m) { m = l2; cl = 2; }
  if (cl == 0) return 0u;
  float s = 1.0f / (expf(l0 - m) + expf(l1 - m) + expf(l2 - m));
  return __float_as_uint(s) | 0x80000000u; // positive float -> monotonic uint
}

// K1 (WIDE, 2080 blocks — proven ~13 us): u8 bins + per-chunk u16 hist.
__global__ __launch_bounds__(256) void k_bins(Ptrs p, uint8_t* bins, uint16_t* hist) {
  int bid = blockIdx.x;
  int b = bid / NCHUNK, chunk = bid % NCHUNK;
  int t = threadIdx.x;
  __shared__ uint32_t lh[256];
  lh[t] = 0;
  __syncthreads();
  int n0 = chunk * CHUNK + t * 4;
  if (n0 < N_ANCH) {                           // quads never straddle N_ANCH (65648%4==0)
    uchar4 v; uint8_t* vb = (uint8_t*)&v;
#pragma unroll
    for (int u = 0; u < 4; ++u) {
      uint32_t key = anchor_key(p, b, n0 + u);
      uint8_t bin = key ? (uint8_t)((key - KBASE) >> 16) : (uint8_t)0;
      vb[u] = bin;
      if (bin) atomicAdd(&lh[bin], 1u);        // LDS only
    }
    *(uchar4*)(bins + (size_t)b * N_ANCH + n0) = v;
  }
  __syncthreads();
  hist[((size_t)b * NCHUNK + chunk) * 256 + t] = (uint16_t)lh[t];
}

// K2 (256 blocks = 32 batches x 8 slices, 256 thr): redundant threshold (proven-cheap
// wide pattern), scan own bin slice, exact keys inline for qualifiers, write private
// per-(batch,slice) segment + count. Zero global atomics.
__global__ __launch_bounds__(256) void k_mid(Ptrs p, const uint8_t* bins,
                                             const uint16_t* hist,
                                             unsigned long long* seg, uint32_t* cnt) {
  int bid = blockIdx.x;
  int b = bid / NSLICE, sl = bid % NSLICE;
  int t = threadIdx.x;
  __shared__ uint32_t tot[256];
  __shared__ int s_thr;
  __shared__ uint32_t s_cnt;

  // threshold: sum 65 chunk hists (4 accumulators), suffix scan, same rule
  const uint16_t* hb = hist + (size_t)b * NCHUNK * 256;
  uint32_t v0 = 0, v1 = 0, v2 = 0, v3 = 0;
  int ch = 0;
  for (; ch + 4 <= NCHUNK; ch += 4) {
    v0 += hb[(ch + 0) * 256 + t];
    v1 += hb[(ch + 1) * 256 + t];
    v2 += hb[(ch + 2) * 256 + t];
    v3 += hb[(ch + 3) * 256 + t];
  }
  for (; ch < NCHUNK; ++ch) v0 += hb[ch * 256 + t];
  tot[t] = v0 + v1 + v2 + v3;
  if (t == 0) s_cnt = 0;
  __syncthreads();
  for (int d = 1; d < 256; d <<= 1) {          // inclusive suffix sum
    uint32_t add = (t + d < 256) ? tot[t + d] : 0u;
    __syncthreads();
    tot[t] += add;
    __syncthreads();
  }
  uint32_t suf = tot[t], sufn = (t < 255) ? tot[t + 1] : 0u;
  if (suf >= TOPK && sufn < TOPK) s_thr = t;   // exactly one setter
  if (t == 0 && tot[0] < TOPK) s_thr = 0;
  __syncthreads();
  int thr = s_thr; if (thr < 1) thr = 1;       // bin>=1 <=> foreground

  // scan this slice's bins (chunks [sl*9, min(sl*9+9,65))), uint4 = 16 bins
  int ch0 = sl * 9, ch1 = min(ch0 + 9, NCHUNK);
  int q0 = ch0 * 64, q1 = min(ch1 * 64, NQ16);
  const uint4* bp = (const uint4*)(bins + (size_t)b * N_ANCH);
  unsigned long long* sg = seg + (size_t)bid * SEGCAP;
  for (int i = q0 + t; i < q1; i += 256) {
    uint4 v4 = bp[i];
    uint32_t ws[4] = { v4.x, v4.y, v4.z, v4.w };
#pragma unroll
    for (int w = 0; w < 4; ++w) {
      uint32_t wv = ws[w];
      if (!wv) continue;
#pragma unroll
      for (int u = 0; u < 4; ++u) {
        int bin = (wv >> (8 * u)) & 0xFF;
        if (bin >= thr) {
          uint32_t pos = atomicAdd(&s_cnt, 1u);          // LDS only
          if (pos < SEGCAP) {
            int n = i * 16 + w * 4 + u;
            uint32_t key = anchor_key(p, b, n);          // exact, L3-warm
            sg[pos] = ((unsigned long long)key << 32) | (uint32_t)(~(uint32_t)n);
          }
        }
      }
    }
  }
  __syncthreads();
  if (t == 0) cnt[bid] = s_cnt;                          // pure store
}

// rank-selection, stride 64 (single wave); s_all zero-padded to multiple of 8.
template<int U>
__device__ inline void rank_sel64(const unsigned long long* s_all, int c, int c8, int t,
                                  unsigned long long* top) {
  unsigned long long mine[U]; int rk[U];
#pragma unroll
  for (int u = 0; u < U; ++u) {
    int i = t + u * 64;
    mine[u] = (i < c) ? s_all[i] : 0ull;
    rk[u] = 0;
  }
  for (int j = 0; j < c8; j += 8) {
    unsigned long long v0 = s_all[j+0], v1 = s_all[j+1], v2 = s_all[j+2], v3 = s_all[j+3];
    unsigned long long v4 = s_all[j+4], v5 = s_all[j+5], v6 = s_all[j+6], v7 = s_all[j+7];
#pragma unroll
    for (int u = 0; u < U; ++u) {
      rk[u] += (v0 > mine[u]) + (v1 > mine[u]) + (v2 > mine[u]) + (v3 > mine[u])
             + (v4 > mine[u]) + (v5 > mine[u]) + (v6 > mine[u]) + (v7 > mine[u]);
    }
  }
#pragma unroll
  for (int u = 0; u < U; ++u) {
    int i = t + u * 64;
    if (i < c && rk[u] < TOPK) top[rk[u]] = mine[u];   // unique u64s -> unique ranks
  }
}

// K3 (32 blocks x 64 threads = ONE wave; __syncthreads compiles to waitcnt only):
// gather <=CAP cands from 8 segments, rank-select, decode, shfl NMS, write.
__global__ __launch_bounds__(64) void k_nms(Ptrs p, const uint32_t* cnt,
                                            const unsigned long long* seg, float* out) {
  int b = blockIdx.x, t = threadIdx.x;
  __shared__ unsigned long long s_all[CAP + 8];
  __shared__ unsigned long long top[TOPK];
  __shared__ float bx1[TOPK], by1[TOPK], bx2[TOPK], by2[TOPK], area[TOPK], sc[TOPK];
  __shared__ int cls_s[TOPK], keep[TOPK];

  // per-slice prefix (each lane computes all 8 — broadcast loads)
  uint32_t pf[NSLICE + 1];
  pf[0] = 0;
#pragma unroll
  for (int s = 0; s < NSLICE; ++s) {
    uint32_t cs = cnt[b * NSLICE + s];
    if (cs > SEGCAP) cs = SEGCAP;
    pf[s + 1] = pf[s] + cs;
  }
  int c = (int)min(pf[NSLICE], (uint32_t)CAP);
  int c8 = (c + 7) & ~7;

  for (int i = t; i < c; i += 64) {
    int s = 0;
#pragma unroll
    for (int q = 1; q < NSLICE; ++q) if (i >= (int)pf[q]) s = q;
    s_all[i] = seg[((size_t)b * NSLICE + s) * SEGCAP + (i - (int)pf[s])];
  }
  for (int i = c + t; i < c8; i += 64) s_all[i] = 0ull;
  for (int r = t; r < TOPK; r += 64) top[r] = 0ull;
  __syncthreads();

  if      (c <= 64)  rank_sel64<1>(s_all, c, c8, t, top);
  else if (c <= 128) rank_sel64<2>(s_all, c, c8, t, top);
  else if (c <= 256) rank_sel64<4>(s_all, c, c8, t, top);
  else if (c <= 512) rank_sel64<8>(s_all, c, c8, t, top);
  else               rank_sel64<16>(s_all, c, c8, t, top);
  __syncthreads();

  // decode top-100 (ranks t and t+64)
  for (int r = t; r < TOPK; r += 64) {
    unsigned long long pk = top[r];
    if (pk == 0ull) {
      sc[r] = -1.f; cls_s[r] = 0; keep[r] = 0;
      bx1[r] = by1[r] = bx2[r] = by2[r] = 0.f; area[r] = 1.f;
    } else {
      uint32_t key = (uint32_t)(pk >> 32);
      int n = (int)(~(uint32_t)pk);
      float score = __uint_as_float(key & 0x7FFFFFFFu);
      int k2 = 0;
#pragma unroll
      for (int q = 1; q < 8; ++q) if (n >= c_off[q]) k2 = q;
      int local = n - c_off[k2];
      int w = c_sz[k2], hw = w * w;
      int i2 = local / w, j2 = local % w;
      const float* cp = p.cls[k2] + (size_t)(b * 3) * hw + local;
      float l0 = cp[0], l1 = cp[(size_t)hw], l2 = cp[(size_t)2 * hw];
      float m = l0; int cl = 0;
      if (l1 > m) { m = l1; cl = 1; }
      if (l2 > m) { m = l2; cl = 2; }
      const float* rp = p.reg[k2] + (size_t)(b * 4) * hw + local;
      float r0 = rp[0], r1 = rp[(size_t)hw], r2 = rp[(size_t)2 * hw], r3 = rp[(size_t)3 * hw];
      float st = c_st[k2], rf = c_rf[k2];
      float cx = (float)j2 * st + st * 0.5f;
      float cy = (float)i2 * st + st * 0.5f;
      float x1 = cx - r0 * rf, y1 = cy - r1 * rf;
      float x2 = cx + r2 * rf, y2 = cy + r3 * rf;
      sc[r] = score; cls_s[r] = cl;
      bx1[r] = x1; by1[r] = y1; bx2[r] = x2; by2[r] = y2;
      area[r] = (x2 - x1 + 1.0f) * (y2 - y1 + 1.0f);
      keep[r] = (score >= 0.35f && cl > 0) ? 1 : 0;
    }
  }
  __syncthreads();

  // greedy NMS in a single wave: lane l owns ranks l and l+64; zero barriers
  {
    int r0 = t, r1 = t + 64;
    float a1x = bx1[r0], a1y = by1[r0], a2x = bx2[r0], a2y = by2[r0], aA = area[r0];
    int k0 = keep[r0];
    bool has1 = (r1 < TOPK);
    float c1x = 0.f, c1y = 0.f, c2x = 0.f, c2y = 0.f, cA = 1.f;
    int k1 = 0;
    if (has1) { c1x = bx1[r1]; c1y = by1[r1]; c2x = bx2[r1]; c2y = by2[r1]; cA = area[r1]; k1 = keep[r1]; }
    for (int i = 0; i < TOPK; ++i) {
      int ol = i & 63, sl = i >> 6;
      int   ki  = __shfl(sl ? k1  : k0,  ol);
      float ix1 = __shfl(sl ? c1x : a1x, ol);
      float iy1 = __shfl(sl ? c1y : a1y, ol);
      float ix2 = __shfl(sl ? c2x : a2x, ol);
      float iy2 = __shfl(sl ? c2y : a2y, ol);
      float iA  = __shfl(sl ? cA  : aA,  ol);
      if (ki) {
        if (k0 && r0 > i) {
          float xmin = fmaxf(ix1, a1x), ymin = fmaxf(iy1, a1y);
          float xmax = fminf(ix2, a2x), ymax = fminf(iy2, a2y);
          float inter = fmaxf(xmax - xmin, 0.f) * fmaxf(ymax - ymin, 0.f);
          float iou = inter / (iA + aA - inter);
          if (iou > 0.5f) k0 = 0;
        }
        if (has1 && k1 && r1 > i) {
          float xmin = fmaxf(ix1, c1x), ymin = fmaxf(iy1, c1y);
          float xmax = fminf(ix2, c2x), ymax = fminf(iy2, c2y);
          float inter = fmaxf(xmax - xmin, 0.f) * fmaxf(ymax - ymin, 0.f);
          float iou = inter / (iA + cA - inter);
          if (iou > 0.5f) k1 = 0;
        }
      }
    }
    keep[r0] = k0;
    if (has1) keep[r1] = k1;
  }
  __syncthreads();

  for (int r = t; r < TOPK; r += 64) {
    int o = b * TOPK + r;
    bool kp = keep[r] != 0;
    out[o] = kp ? sc[r] : 0.f;                                  // scores
    out[NBATCH * TOPK + o] = kp ? (float)cls_s[r] : 0.f;        // classes
    float* ob = out + 2 * NBATCH * TOPK + (size_t)o * 4;        // boxes
    ob[0] = kp ? bx1[r] : 0.f;
    ob[1] = kp ? by1[r] : 0.f;
    ob[2] = kp ? bx2[r] : 0.f;
    ob[3] = kp ? by2[r] : 0.f;
    out[6 * NBATCH * TOPK + o] = kp ? 1.f : 0.f;                // keep
  }
}

extern "C" void kernel_launch(void* const* d_in, const int* in_sizes, int n_in,
                              void* d_out, int out_size, void* d_ws, size_t ws_size,
                              hipStream_t stream) {
  Ptrs p;
  // setup_inputs() dict order is INTERLEAVED: cls0, reg0, cls1, reg1, ...
  for (int i = 0; i < 8; ++i) {
    p.cls[i] = (const float*)d_in[2 * i];
    p.reg[i] = (const float*)d_in[2 * i + 1];
  }
  uint8_t*  bins = (uint8_t*)d_ws;                               // 2,100,736 B
  uint16_t* hist = (uint16_t*)((char*)d_ws + 2100736);           // 1,064,960 B
  uint32_t* cnt  = (uint32_t*)((char*)d_ws + 3165696);           // 32*8*4 = 1,024 B
  unsigned long long* seg =
      (unsigned long long*)((char*)d_ws + 3166720);              // 32*8*1024*8 = 2,097,152 B
  float* out = (float*)d_out;                                    // total ws ≈ 5.3 MB

  k_bins<<<NBATCH * NCHUNK, 256, 0, stream>>>(p, bins, hist);
  k_mid<<<NBATCH * NSLICE, 256, 0, stream>>>(p, bins, hist, seg, cnt);
  k_nms<<<NBATCH, 64, 0, stream>>>(p, cnt, seg, out);
}

// Round 15
// 66.675 us; speedup vs baseline: 1.0093x; 1.0093x over previous
//
#include <hip/hip_runtime.h>
#include <stdint.h>

#define N_ANCH 65648
#define NCHUNK 65          // k_bins chunks of 1024 anchors
#define CHUNK  1024
#define NQ16   4103        // 65648/16
#define CAP    2048        // candidate capacity (LDS)
#define KBASE  0xBE800000u // sortable key of 0.25; fg scores >= 1/3 -> bins in [42,255]
#define NBATCH 32
#define TOPK   100
#define FT     512         // k_sel threads; U = CAP/FT = 4 fixed

struct Ptrs { const float* cls[8]; const float* reg[8]; };

__constant__ int   c_off[9] = {0,25281,50562,56803,63044,64565,64926,65287,65648};
__constant__ int   c_sz[8]  = {159,159,79,79,39,19,19,19};
__constant__ float c_st[8]  = {4.f,4.f,8.f,8.f,16.f,32.f,32.f,32.f};
__constant__ float c_rf[8]  = {27.5f,35.5f,55.5f,71.5f,111.5f,191.5f,255.5f,319.5f};

// sortable key for the masked score of anchor n in batch b; 0 if background.
// EXACT same fp sequence as all passing rounds.
__device__ inline uint32_t anchor_key(const Ptrs& p, int b, int n) {
  int k = 0;
#pragma unroll
  for (int q = 1; q < 8; ++q) if (n >= c_off[q]) k = q;
  int local = n - c_off[k];
  int hw = c_sz[k] * c_sz[k];
  const float* c = p.cls[k] + (size_t)(b * 3) * hw + local;
  float l0 = c[0], l1 = c[(size_t)hw], l2 = c[(size_t)2 * hw];
  float m = l0; int cl = 0;
  if (l1 > m) { m = l1; cl = 1; }
  if (l2 > m) { m = l2; cl = 2; }
  if (cl == 0) return 0u;
  float s = 1.0f / (expf(l0 - m) + expf(l1 - m) + expf(l2 - m));
  return __float_as_uint(s) | 0x80000000u; // positive float -> monotonic uint
}

// K1 (WIDE, 2080 blocks — proven ~13 us, byte-identical to r13): u8 bins + u16 hist.
__global__ __launch_bounds__(256) void k_bins(Ptrs p, uint8_t* bins, uint16_t* hist) {
  int bid = blockIdx.x;
  int b = bid / NCHUNK, chunk = bid % NCHUNK;
  int t = threadIdx.x;
  __shared__ uint32_t lh[256];
  lh[t] = 0;
  __syncthreads();
  int n0 = chunk * CHUNK + t * 4;
  if (n0 < N_ANCH) {
    uchar4 v; uint8_t* vb = (uint8_t*)&v;
#pragma unroll
    for (int u = 0; u < 4; ++u) {
      uint32_t key = anchor_key(p, b, n0 + u);
      uint8_t bin = key ? (uint8_t)((key - KBASE) >> 16) : (uint8_t)0;
      vb[u] = bin;
      if (bin) atomicAdd(&lh[bin], 1u);        // LDS only
    }
    *(uchar4*)(bins + (size_t)b * N_ANCH + n0) = v;
  }
  __syncthreads();
  hist[((size_t)b * NCHUNK + chunk) * 256 + t] = (uint16_t)lh[t];
}

// K2 (32 blocks x 512 thr): AUSTERE tail — minimal instruction footprint.
// threshold -> bin scan -> exact keys -> single rank_select (U=4) -> decode -> NMS.
__global__ __launch_bounds__(FT) void k_sel(Ptrs p, const uint8_t* bins,
                                            const uint16_t* hist, float* out) {
  int b = blockIdx.x, t = threadIdx.x;
  __shared__ uint32_t tot[256];
  __shared__ int s_idx[CAP];
  __shared__ unsigned long long s_all[CAP];
  __shared__ unsigned long long top[TOPK];
  __shared__ float bx1[TOPK], by1[TOPK], bx2[TOPK], by2[TOPK], area[TOPK], sc[TOPK];
  __shared__ int cls_s[TOPK], keep[TOPK];
  __shared__ uint32_t s_cnt;
  __shared__ int s_thr;

  // ---- threshold: sum 65 chunk hists (2 half-sums via 512 threads), suffix scan ----
  {
    const uint16_t* hb = hist + (size_t)b * NCHUNK * 256 + (t & 255);
    int g = t >> 8;                           // 0 or 1: split chunks
    uint32_t v = 0;
    for (int ch = g; ch < NCHUNK; ch += 2) v += hb[ch * 256];
    if (g == 0) tot[t] = v;
    if (t == 0) s_cnt = 0;
    __syncthreads();
    if (g) tot[t & 255] += v;
    __syncthreads();
    for (int d = 1; d < 256; d <<= 1) {
      uint32_t add = 0;
      if (t < 256 && t + d < 256) add = tot[t + d];
      __syncthreads();
      if (t < 256) tot[t] += add;
      __syncthreads();
    }
    if (t < 256) {
      uint32_t suf = tot[t], sufn = (t < 255) ? tot[t + 1] : 0u;
      if (suf >= TOPK && sufn < TOPK) s_thr = t;
      if (t == 0 && tot[0] < TOPK) s_thr = 0;
    }
    __syncthreads();
  }
  uint32_t thr = (uint32_t)max(s_thr, 1);     // bin>=1 <=> foreground

  // ---- scan 64KB bins (uint4 = 16 bins), collect indices via LDS atomic ----
  {
    const uint4* bp = (const uint4*)(bins + (size_t)b * N_ANCH);
    for (int i = t; i < NQ16; i += FT) {
      uint4 v4 = bp[i];
      uint32_t ws[4] = { v4.x, v4.y, v4.z, v4.w };
      for (int w = 0; w < 4; ++w) {           // not unrolled beyond natural
        uint32_t wv = ws[w];
        if (!wv) continue;
        for (int u = 0; u < 4; ++u) {
          if (((wv >> (8 * u)) & 0xFFu) >= thr) {
            uint32_t q = atomicAdd(&s_cnt, 1u);
            if (q < CAP) s_idx[q] = i * 16 + w * 4 + u;
          }
        }
      }
    }
  }
  __syncthreads();
  int c = (int)min(s_cnt, (uint32_t)CAP);

  // ---- exact keys for c candidates; pad to CAP with 0 ----
  for (int i = t; i < CAP; i += FT) {
    unsigned long long v = 0ull;
    if (i < c) {
      int n = s_idx[i];
      v = ((unsigned long long)anchor_key(p, b, n) << 32) | (uint32_t)(~(uint32_t)n);
    }
    s_all[i] = v;
  }
  if (t < TOPK) top[t] = 0ull;
  __syncthreads();

  // ---- single rank_select: U=4, plain loop over c (zeros never outrank) ----
  {
    unsigned long long m0 = s_all[t], m1 = s_all[t + FT],
                       m2 = s_all[t + 2 * FT], m3 = s_all[t + 3 * FT];
    int r0 = 0, r1 = 0, r2 = 0, r3 = 0;
    for (int j = 0; j < c; j += 2) {
      unsigned long long va = s_all[j], vb = s_all[j + 1];  // c padded region safe
      r0 += (va > m0) + (vb > m0);
      r1 += (va > m1) + (vb > m1);
      r2 += (va > m2) + (vb > m2);
      r3 += (va > m3) + (vb > m3);
    }
    if (m0 && r0 < TOPK) top[r0] = m0;
    if (m1 && r1 < TOPK) top[r1] = m1;
    if (m2 && r2 < TOPK) top[r2] = m2;
    if (m3 && r3 < TOPK) top[r3] = m3;
  }
  __syncthreads();

  // ---- decode top-100 ----
  if (t < TOPK) {
    int r = t;
    unsigned long long pk = top[r];
    if (pk == 0ull) {
      sc[r] = -1.f; cls_s[r] = 0; keep[r] = 0;
      bx1[r] = by1[r] = bx2[r] = by2[r] = 0.f; area[r] = 1.f;
    } else {
      uint32_t key = (uint32_t)(pk >> 32);
      int n = (int)(~(uint32_t)pk);
      float score = __uint_as_float(key & 0x7FFFFFFFu);
      int k2 = 0;
#pragma unroll
      for (int q = 1; q < 8; ++q) if (n >= c_off[q]) k2 = q;
      int local = n - c_off[k2];
      int w = c_sz[k2], hw = w * w;
      int i2 = local / w, j2 = local % w;
      const float* cp = p.cls[k2] + (size_t)(b * 3) * hw + local;
      float l0 = cp[0], l1 = cp[(size_t)hw], l2 = cp[(size_t)2 * hw];
      float m = l0; int cl = 0;
      if (l1 > m) { m = l1; cl = 1; }
      if (l2 > m) { m = l2; cl = 2; }
      const float* rp = p.reg[k2] + (size_t)(b * 4) * hw + local;
      float r0 = rp[0], r1 = rp[(size_t)hw], r2 = rp[(size_t)2 * hw], r3 = rp[(size_t)3 * hw];
      float st = c_st[k2], rf = c_rf[k2];
      float cx = (float)j2 * st + st * 0.5f;
      float cy = (float)i2 * st + st * 0.5f;
      float x1 = cx - r0 * rf, y1 = cy - r1 * rf;
      float x2 = cx + r2 * rf, y2 = cy + r3 * rf;
      sc[r] = score; cls_s[r] = cl;
      bx1[r] = x1; by1[r] = y1; bx2[r] = x2; by2[r] = y2;
      area[r] = (x2 - x1 + 1.0f) * (y2 - y1 + 1.0f);
      keep[r] = (score >= 0.35f && cl > 0) ? 1 : 0;
    }
  }
  __syncthreads();

  // ---- greedy NMS in one wave: lane l owns ranks l and l+64 ----
  if (t < 64) {
    int r0 = t, r1 = t + 64;
    float a1x = bx1[r0], a1y = by1[r0], a2x = bx2[r0], a2y = by2[r0], aA = area[r0];
    int k0 = keep[r0];
    bool has1 = (r1 < TOPK);
    float c1x = 0.f, c1y = 0.f, c2x = 0.f, c2y = 0.f, cA = 1.f;
    int k1 = 0;
    if (has1) { c1x = bx1[r1]; c1y = by1[r1]; c2x = bx2[r1]; c2y = by2[r1]; cA = area[r1]; k1 = keep[r1]; }
    for (int i = 0; i < TOPK; ++i) {
      int ol = i & 63, sl = i >> 6;
      int   ki  = __shfl(sl ? k1  : k0,  ol);
      float ix1 = __shfl(sl ? c1x : a1x, ol);
      float iy1 = __shfl(sl ? c1y : a1y, ol);
      float ix2 = __shfl(sl ? c2x : a2x, ol);
      float iy2 = __shfl(sl ? c2y : a2y, ol);
      float iA  = __shfl(sl ? cA  : aA,  ol);
      if (ki) {
        if (k0 && r0 > i) {
          float xmin = fmaxf(ix1, a1x), ymin = fmaxf(iy1, a1y);
          float xmax = fminf(ix2, a2x), ymax = fminf(iy2, a2y);
          float inter = fmaxf(xmax - xmin, 0.f) * fmaxf(ymax - ymin, 0.f);
          float iou = inter / (iA + aA - inter);
          if (iou > 0.5f) k0 = 0;
        }
        if (has1 && k1 && r1 > i) {
          float xmin = fmaxf(ix1, c1x), ymin = fmaxf(iy1, c1y);
          float xmax = fminf(ix2, c2x), ymax = fminf(iy2, c2y);
          float inter = fmaxf(xmax - xmin, 0.f) * fmaxf(ymax - ymin, 0.f);
          float iou = inter / (iA + cA - inter);
          if (iou > 0.5f) k1 = 0;
        }
      }
    }
    keep[r0] = k0;
    if (has1) keep[r1] = k1;
  }
  __syncthreads();

  if (t < TOPK) {
    int r = t, o = b * TOPK + r;
    bool kp = keep[r] != 0;
    out[o] = kp ? sc[r] : 0.f;                                  // scores
    out[NBATCH * TOPK + o] = kp ? (float)cls_s[r] : 0.f;        // classes
    float* ob = out + 2 * NBATCH * TOPK + (size_t)o * 4;        // boxes
    ob[0] = kp ? bx1[r] : 0.f;
    ob[1] = kp ? by1[r] : 0.f;
    ob[2] = kp ? bx2[r] : 0.f;
    ob[3] = kp ? by2[r] : 0.f;
    out[6 * NBATCH * TOPK + o] = kp ? 1.f : 0.f;                // keep
  }
}

extern "C" void kernel_launch(void* const* d_in, const int* in_sizes, int n_in,
                              void* d_out, int out_size, void* d_ws, size_t ws_size,
                              hipStream_t stream) {
  Ptrs p;
  // setup_inputs() dict order is INTERLEAVED: cls0, reg0, cls1, reg1, ...
  for (int i = 0; i < 8; ++i) {
    p.cls[i] = (const float*)d_in[2 * i];
    p.reg[i] = (const float*)d_in[2 * i + 1];
  }
  uint8_t*  bins = (uint8_t*)d_ws;                               // 2,100,736 B
  uint16_t* hist = (uint16_t*)((char*)d_ws + 2100736);           // 1,064,960 B
  float* out = (float*)d_out;

  k_bins<<<NBATCH * NCHUNK, 256, 0, stream>>>(p, bins, hist);
  k_sel<<<NBATCH, FT, 0, stream>>>(p, bins, hist, out);
}

// Round 16
// 49.162 us; speedup vs baseline: 1.3688x; 1.3562x over previous
//
#include <hip/hip_runtime.h>
#include <stdint.h>

#define N_ANCH 65648
#define NCHUNK 65          // k_bins chunks of 1024 anchors
#define CHUNK  1024
#define NQ16   4103        // 65648/16
#define CAP    2048        // candidate capacity (LDS)
#define KBASE  0xBE800000u // sortable key of 0.25; fg scores >= 1/3 -> bins in [42,255]
#define NBATCH 32
#define TOPK   100
#define FT     1024        // k_sel threads

struct Ptrs { const float* cls[8]; const float* reg[8]; };

__constant__ int   c_off[9] = {0,25281,50562,56803,63044,64565,64926,65287,65648};
__constant__ int   c_sz[8]  = {159,159,79,79,39,19,19,19};
__constant__ float c_st[8]  = {4.f,4.f,8.f,8.f,16.f,32.f,32.f,32.f};
__constant__ float c_rf[8]  = {27.5f,35.5f,55.5f,71.5f,111.5f,191.5f,255.5f,319.5f};

// sortable key for the masked score of anchor n in batch b; 0 if background.
// EXACT same fp sequence as all passing rounds.
__device__ inline uint32_t anchor_key(const Ptrs& p, int b, int n) {
  int k = 0;
#pragma unroll
  for (int q = 1; q < 8; ++q) if (n >= c_off[q]) k = q;
  int local = n - c_off[k];
  int hw = c_sz[k] * c_sz[k];
  const float* c = p.cls[k] + (size_t)(b * 3) * hw + local;
  float l0 = c[0], l1 = c[(size_t)hw], l2 = c[(size_t)2 * hw];
  float m = l0; int cl = 0;
  if (l1 > m) { m = l1; cl = 1; }
  if (l2 > m) { m = l2; cl = 2; }
  if (cl == 0) return 0u;
  float s = 1.0f / (expf(l0 - m) + expf(l1 - m) + expf(l2 - m));
  return __float_as_uint(s) | 0x80000000u; // positive float -> monotonic uint
}

// K1 (WIDE, 2080 blocks — proven ~13 us, byte-identical to r13): u8 bins + u16 hist.
__global__ __launch_bounds__(256) void k_bins(Ptrs p, uint8_t* bins, uint16_t* hist) {
  int bid = blockIdx.x;
  int b = bid / NCHUNK, chunk = bid % NCHUNK;
  int t = threadIdx.x;
  __shared__ uint32_t lh[256];
  lh[t] = 0;
  __syncthreads();
  int n0 = chunk * CHUNK + t * 4;
  if (n0 < N_ANCH) {
    uchar4 v; uint8_t* vb = (uint8_t*)&v;
#pragma unroll
    for (int u = 0; u < 4; ++u) {
      uint32_t key = anchor_key(p, b, n0 + u);
      uint8_t bin = key ? (uint8_t)((key - KBASE) >> 16) : (uint8_t)0;
      vb[u] = bin;
      if (bin) atomicAdd(&lh[bin], 1u);        // LDS only
    }
    *(uchar4*)(bins + (size_t)b * N_ANCH + n0) = v;
  }
  __syncthreads();
  hist[((size_t)b * NCHUNK + chunk) * 256 + t] = (uint16_t)lh[t];
}

// rank-selection with 8-deep batched LDS broadcast reads; s_all zero-padded to
// a multiple of 8 (zeros never outrank real keys).
template<int U>
__device__ inline void rank_select(const unsigned long long* s_all, int c, int c8, int t,
                                   unsigned long long* top) {
  unsigned long long mine[U]; int rk[U];
#pragma unroll
  for (int u = 0; u < U; ++u) {
    int i = t + u * FT;
    mine[u] = (i < c) ? s_all[i] : 0ull;
    rk[u] = 0;
  }
  for (int j = 0; j < c8; j += 8) {
    unsigned long long v0 = s_all[j+0], v1 = s_all[j+1], v2 = s_all[j+2], v3 = s_all[j+3];
    unsigned long long v4 = s_all[j+4], v5 = s_all[j+5], v6 = s_all[j+6], v7 = s_all[j+7];
#pragma unroll
    for (int u = 0; u < U; ++u) {
      rk[u] += (v0 > mine[u]) + (v1 > mine[u]) + (v2 > mine[u]) + (v3 > mine[u])
             + (v4 > mine[u]) + (v5 > mine[u]) + (v6 > mine[u]) + (v7 > mine[u]);
    }
  }
#pragma unroll
  for (int u = 0; u < U; ++u) {
    int i = t + u * FT;
    if (i < c && rk[u] < TOPK) top[rk[u]] = mine[u];   // unique u64s -> unique ranks
  }
}

// K2 (32 blocks x 1024): ILP'd threshold -> bin scan -> exact keys -> rank-select
// -> decode -> PAIRWISE-MASK NMS (no cross-lane serial chain) -> out.
__global__ __launch_bounds__(FT) void k_sel(Ptrs p, const uint8_t* bins,
                                            const uint16_t* hist, float* out) {
  int b = blockIdx.x, t = threadIdx.x;
  __shared__ uint32_t part[4][256];
  __shared__ uint32_t tot[256];
  __shared__ int s_idx[CAP];
  __shared__ unsigned long long s_all[CAP + 8];
  __shared__ unsigned long long top[TOPK];
  __shared__ float bx1[TOPK], by1[TOPK], bx2[TOPK], by2[TOPK], area[TOPK], sc[TOPK];
  __shared__ int cls_s[TOPK], keep[TOPK];
  __shared__ unsigned long long sup0[TOPK], sup1[TOPK];
  __shared__ unsigned long long s_km[2], s_km2[2];
  __shared__ uint32_t s_cnt;
  __shared__ int s_thr;

  // ---- threshold: 4 groups x 4-deep accumulators (5 rounds of 4 indep loads) ----
  {
    const uint16_t* hb = hist + (size_t)b * NCHUNK * 256;
    int g = t >> 8, tb = t & 255;
    uint32_t v0 = 0, v1 = 0, v2 = 0, v3 = 0;
    for (int ch = g; ch < NCHUNK; ch += 16) {
      v0 += hb[ch * 256 + tb];
      if (ch + 4 < NCHUNK)  v1 += hb[(ch + 4) * 256 + tb];
      if (ch + 8 < NCHUNK)  v2 += hb[(ch + 8) * 256 + tb];
      if (ch + 12 < NCHUNK) v3 += hb[(ch + 12) * 256 + tb];
    }
    part[g][tb] = v0 + v1 + v2 + v3;
    if (t == 0) s_cnt = 0;
    if (t < TOPK) top[t] = 0ull;
    __syncthreads();
    if (t < 256) tot[t] = part[0][t] + part[1][t] + part[2][t] + part[3][t];
    __syncthreads();
    for (int d = 1; d < 256; d <<= 1) {            // inclusive suffix sum
      uint32_t add = 0;
      if (t < 256 && t + d < 256) add = tot[t + d];
      __syncthreads();
      if (t < 256) tot[t] += add;
      __syncthreads();
    }
    if (t < 256) {
      uint32_t suf = tot[t], sufn = (t < 255) ? tot[t + 1] : 0u;
      if (suf >= TOPK && sufn < TOPK) s_thr = t;   // exactly one setter
      if (t == 0 && tot[0] < TOPK) s_thr = 0;
    }
    __syncthreads();
  }
  int thr = s_thr; if (thr < 1) thr = 1;           // bin>=1 <=> foreground

  // ---- scan 64KB bins (uint4 = 16 bins, 4 rounds/thread), collect indices ----
  {
    const uint4* bp = (const uint4*)(bins + (size_t)b * N_ANCH);
    for (int i = t; i < NQ16; i += FT) {
      uint4 v4 = bp[i];
      uint32_t ws[4] = { v4.x, v4.y, v4.z, v4.w };
#pragma unroll
      for (int w = 0; w < 4; ++w) {
        uint32_t wv = ws[w];
        if (!wv) continue;
#pragma unroll
        for (int u = 0; u < 4; ++u) {
          int bin = (wv >> (8 * u)) & 0xFF;
          if (bin >= thr) {
            uint32_t q = atomicAdd(&s_cnt, 1u);
            if (q < CAP) s_idx[q] = i * 16 + w * 4 + u;
          }
        }
      }
    }
  }
  __syncthreads();
  int c = (int)min(s_cnt, (uint32_t)CAP);
  int c8 = (c + 7) & ~7;

  // ---- exact keys only for c candidates (cls L2/L3-warm) ----
  for (int i = t; i < c; i += FT) {
    int n = s_idx[i];
    s_all[i] = ((unsigned long long)anchor_key(p, b, n) << 32) | (uint32_t)(~(uint32_t)n);
  }
  for (int i = c + t; i < c8; i += FT) s_all[i] = 0ull;   // pad
  __syncthreads();

  if (c <= FT) rank_select<1>(s_all, c, c8, t, top);
  else         rank_select<2>(s_all, c, c8, t, top);
  __syncthreads();

  // ---- decode top-100 ----
  if (t < TOPK) {
    int r = t;
    unsigned long long pk = top[r];
    if (pk == 0ull) {
      sc[r] = -1.f; cls_s[r] = 0; keep[r] = 0;
      bx1[r] = by1[r] = bx2[r] = by2[r] = 0.f; area[r] = 1.f;
    } else {
      uint32_t key = (uint32_t)(pk >> 32);
      int n = (int)(~(uint32_t)pk);
      float score = __uint_as_float(key & 0x7FFFFFFFu);
      int k2 = 0;
#pragma unroll
      for (int q = 1; q < 8; ++q) if (n >= c_off[q]) k2 = q;
      int local = n - c_off[k2];
      int w = c_sz[k2], hw = w * w;
      int i2 = local / w, j2 = local % w;
      const float* cp = p.cls[k2] + (size_t)(b * 3) * hw + local;
      float l0 = cp[0], l1 = cp[(size_t)hw], l2 = cp[(size_t)2 * hw];
      float m = l0; int cl = 0;
      if (l1 > m) { m = l1; cl = 1; }
      if (l2 > m) { m = l2; cl = 2; }
      const float* rp = p.reg[k2] + (size_t)(b * 4) * hw + local;
      float r0 = rp[0], r1 = rp[(size_t)hw], r2 = rp[(size_t)2 * hw], r3 = rp[(size_t)3 * hw];
      float st = c_st[k2], rf = c_rf[k2];
      float cx = (float)j2 * st + st * 0.5f;
      float cy = (float)i2 * st + st * 0.5f;
      float x1 = cx - r0 * rf, y1 = cy - r1 * rf;
      float x2 = cx + r2 * rf, y2 = cy + r3 * rf;
      sc[r] = score; cls_s[r] = cl;
      bx1[r] = x1; by1[r] = y1; bx2[r] = x2; by2[r] = y2;
      area[r] = (x2 - x1 + 1.0f) * (y2 - y1 + 1.0f);
      keep[r] = (score >= 0.35f && cl > 0) ? 1 : 0;
    }
  }
  __syncthreads();

  // ---- NMS stage A: thread i computes its suppression row (bits j>i, iou>0.5) ----
  if (t < TOPK) {
    float a1x = bx1[t], a1y = by1[t], a2x = bx2[t], a2y = by2[t], aA = area[t];
    unsigned long long m0 = 0, m1 = 0;
    for (int j = t + 1; j < TOPK; ++j) {
      float xmin = fmaxf(a1x, bx1[j]), ymin = fmaxf(a1y, by1[j]);
      float xmax = fminf(a2x, bx2[j]), ymax = fminf(a2y, by2[j]);
      float inter = fmaxf(xmax - xmin, 0.f) * fmaxf(ymax - ymin, 0.f);
      float iou = inter / (aA + area[j] - inter);
      if (iou > 0.5f) { if (j < 64) m0 |= 1ull << j; else m1 |= 1ull << (j - 64); }
    }
    sup0[t] = m0; sup1[t] = m1;
  }
  // initial keep mask via wave ballots (waves 0 and 1 of this block)
  if (t < 64) {
    unsigned long long m = __ballot(keep[t] != 0);
    if (t == 0) s_km[0] = m;
  } else if (t < 128) {
    unsigned long long m = __ballot(t < TOPK && keep[t] != 0);
    if (t == 64) s_km[1] = m;
  }
  __syncthreads();

  // ---- NMS stage B: bitset greedy, 8-row prefetched batches (thread 0) ----
  if (t == 0) {
    unsigned long long km0 = s_km[0], km1 = s_km[1];
    for (int i0 = 0; i0 < TOPK; i0 += 8) {
      unsigned long long a0[8], a1[8];
#pragma unroll
      for (int q = 0; q < 8; ++q) {
        int i = i0 + q;
        a0[q] = (i < TOPK) ? sup0[i] : 0ull;
        a1[q] = (i < TOPK) ? sup1[i] : 0ull;
      }
#pragma unroll
      for (int q = 0; q < 8; ++q) {
        int i = i0 + q;
        if (i < TOPK) {
          bool ki = (i < 64) ? ((km0 >> i) & 1) : ((km1 >> (i - 64)) & 1);
          if (ki) { km0 &= ~a0[q]; km1 &= ~a1[q]; }
        }
      }
    }
    s_km2[0] = km0; s_km2[1] = km1;
  }
  __syncthreads();

  if (t < TOPK) {
    int r = t, o = b * TOPK + r;
    bool kp = (r < 64) ? ((s_km2[0] >> r) & 1) : ((s_km2[1] >> (r - 64)) & 1);
    out[o] = kp ? sc[r] : 0.f;                                  // scores
    out[NBATCH * TOPK + o] = kp ? (float)cls_s[r] : 0.f;        // classes
    float* ob = out + 2 * NBATCH * TOPK + (size_t)o * 4;        // boxes
    ob[0] = kp ? bx1[r] : 0.f;
    ob[1] = kp ? by1[r] : 0.f;
    ob[2] = kp ? bx2[r] : 0.f;
    ob[3] = kp ? by2[r] : 0.f;
    out[6 * NBATCH * TOPK + o] = kp ? 1.f : 0.f;                // keep
  }
}

extern "C" void kernel_launch(void* const* d_in, const int* in_sizes, int n_in,
                              void* d_out, int out_size, void* d_ws, size_t ws_size,
                              hipStream_t stream) {
  Ptrs p;
  // setup_inputs() dict order is INTERLEAVED: cls0, reg0, cls1, reg1, ...
  for (int i = 0; i < 8; ++i) {
    p.cls[i] = (const float*)d_in[2 * i];
    p.reg[i] = (const float*)d_in[2 * i + 1];
  }
  uint8_t*  bins = (uint8_t*)d_ws;                               // 2,100,736 B
  uint16_t* hist = (uint16_t*)((char*)d_ws + 2100736);           // 1,064,960 B
  float* out = (float*)d_out;

  k_bins<<<NBATCH * NCHUNK, 256, 0, stream>>>(p, bins, hist);
  k_sel<<<NBATCH, FT, 0, stream>>>(p, bins, hist, out);
}